// Round 3
// baseline (280.429 us; speedup 1.0000x reference)
//
#include <hip/hip_runtime.h>
#include <math.h>

#define FF 2048

typedef __attribute__((ext_vector_type(8))) short short8;
typedef __attribute__((ext_vector_type(4))) float floatx4;

// ws float offsets
#define OFF_SPART 0                      // [8][64][1000]
#define OFF_HPART 512000                 // [8][64][1000]
#define OFF_SELP  1024000                // [4][64][2048]
#define OFF_MEMP  1548288                // [8][64][2048]
#define OFF_LOGP  2596864                // [16][64][1000]
#define OFF_V     3620864                // [64][1000]
#define OFF_FEAT  3684864                // [64][2048]
#define OFF_CN2   3815936                // [1000]
#define OFF_WINV  3816936                // [1000]
#define OFF_XN2   3817936                // [64]
#define OFF_REACH 3818000                // [64]
#define OFF_NRM2P 3818064                // [64][4]
#define OFF_BAR   3818320                // unsigned barrier counter

#define TP 40   // LDS tile pitch in shorts: 32 data + 8 pad, 80 B rows, 16B-aligned

// fp32 -> bf16 hi/lo truncation split
__device__ __forceinline__ void split2(float f, ushort& h, ushort& l) {
  unsigned u = __float_as_uint(f);
  float r = f - __uint_as_float(u & 0xffff0000u);
  h = (ushort)(u >> 16);
  l = (ushort)(__float_as_uint(r) >> 16);
}

// Stage 64 rows x 32 k of row-major-K matrix into hi/lo bf16 LDS tiles [64][TP].
__device__ __forceinline__ void stage_bt_bf(const float* __restrict__ M, int ldK, int rowBase,
                                            int nrows, int k0, int kmax,
                                            ushort* __restrict__ hi, ushort* __restrict__ lo, int t) {
  int r = t >> 2, q = t & 3;
  int grow = rowBase + r;
  bool rok = grow < nrows;
  const float* src = M + (size_t)grow * ldK + k0 + q * 8;
#pragma unroll
  for (int h = 0; h < 2; ++h) {
    int kb = k0 + q * 8 + h * 4;
    float4 v = make_float4(0.f, 0.f, 0.f, 0.f);
    if (rok) {
      if (kb + 3 < kmax) {
        v = *(const float4*)(src + h * 4);
      } else {
#pragma unroll
        for (int j = 0; j < 4; ++j)
          if (kb + j < kmax) ((float*)&v)[j] = src[h * 4 + j];
      }
    }
    ushort4 hv, lv;
    split2(v.x, hv.x, lv.x); split2(v.y, hv.y, lv.y);
    split2(v.z, hv.z, lv.z); split2(v.w, hv.w, lv.w);
    int base = r * TP + q * 8 + h * 4;
    *(ushort4*)(hi + base) = hv;
    *(ushort4*)(lo + base) = lv;
  }
}

// Stage 32 k-rows x 64 n-cols of row-major-N matrix B[k][n] into hi/lo LDS [n][k] (transposed).
__device__ __forceinline__ void stage_tr_bf(const float* __restrict__ M, int ldN, int k0, int kmax,
                                            int n0, ushort* __restrict__ hi, ushort* __restrict__ lo, int t) {
  int kk = t >> 3, c8 = (t & 7) * 8;
  int gk = k0 + kk;
  const float* src = M + (size_t)gk * ldN + n0 + c8;
  float4 v0 = make_float4(0.f, 0.f, 0.f, 0.f), v1 = v0;
  if (gk < kmax) { v0 = *(const float4*)src; v1 = *(const float4*)(src + 4); }
#pragma unroll
  for (int j = 0; j < 8; ++j) {
    float f = (j < 4) ? ((float*)&v0)[j] : ((float*)&v1)[j - 4];
    ushort h, l;
    split2(f, h, l);
    hi[(c8 + j) * TP + kk] = h;
    lo[(c8 + j) * TP + kk] = l;
  }
}

#define MFMA(a, b, c) __builtin_amdgcn_mfma_f32_16x16x32_bf16(a, b, c, 0, 0, 0)

// Monotonic grid barrier: all NBLK blocks arrive; wait until count >= target.
// Counter zeroed by k_init each launch; targets increase per phase (no ABA).
__device__ __forceinline__ void gbar(unsigned* __restrict__ bar, unsigned target) {
  __syncthreads();
  if (threadIdx.x == 0) {
    __threadfence();
    __hip_atomic_fetch_add(bar, 1u, __ATOMIC_RELEASE, __HIP_MEMORY_SCOPE_AGENT);
    while (__hip_atomic_load(bar, __ATOMIC_ACQUIRE, __HIP_MEMORY_SCOPE_AGENT) < target)
      __builtin_amdgcn_s_sleep(2);
    __threadfence();
  }
  __syncthreads();
}

__global__ void k_init(unsigned* bar) {
  if (threadIdx.x == 0)
    __hip_atomic_store(bar, 0u, __ATOMIC_RELAXED, __HIP_MEMORY_SCOPE_AGENT);
}

#define NBLK 256

__global__ __launch_bounds__(256) void k_all(
    const float* __restrict__ x, const float* __restrict__ cent,
    const float* __restrict__ whall, const float* __restrict__ bhall,
    const float* __restrict__ wsel, const float* __restrict__ bsel,
    const float* __restrict__ wcos, float* __restrict__ ws, float* __restrict__ out) {
  __shared__ __align__(16) char smem[6 * 64 * TP * 2];   // 30720 B, aliased per phase
  ushort* Ah  = (ushort*)smem;
  ushort* Al  = Ah + 64 * TP;
  ushort* B1h = Ah + 2 * 64 * TP;
  ushort* B1l = Ah + 3 * 64 * TP;
  ushort* B2h = Ah + 4 * 64 * TP;
  ushort* B2l = Ah + 5 * 64 * TP;
  float* hrow = (float*)smem;            // phase B: [1000]
  float* red  = (float*)smem + 1000;     // phase B/D: [256]

  int bx = blockIdx.x, t = threadIdx.x;
  int lane = t & 63, w = t >> 6;
  int ln15 = t & 15, lq = (t >> 4) & 3, q8 = lq * 8;
  int mh = w & 1, nh = w >> 1;
  unsigned* bar = (unsigned*)(ws + OFF_BAR);

  // ---------------- Phase A: row norms + GEMM1 (S,H dual / selpre) ----------------
  // norms: wave-slot = bx*4+w handles rows slot, slot+1024, slot+2048(<16)
  for (int r = bx * 4 + w; r < 2064; r += 1024) {
    const float* src = (r < 1000) ? cent + (size_t)r * FF
                     : (r < 2000) ? wcos + (size_t)(r - 1000) * FF
                                  : x + (size_t)(r - 2000) * FF;
    float s = 0.f;
#pragma unroll
    for (int i = 0; i < 8; ++i) {
      float4 v = *(const float4*)(src + i * 256 + lane * 4);
      s += v.x * v.x + v.y * v.y + v.z * v.z + v.w * v.w;
    }
#pragma unroll
    for (int off = 32; off > 0; off >>= 1) s += __shfl_down(s, off, 64);
    if (lane == 0) {
      if (r < 1000) ws[OFF_CN2 + r] = s;
      else if (r < 2000) ws[OFF_WINV + (r - 1000)] = 1.f / sqrtf(s);
      else ws[OFF_XN2 + (r - 2000)] = s;
    }
  }

  if (bx < 128) {
    // dual GEMM: S = x@cent^T, H = x@whall^T. 16 tiles x 8 splits, slab 256.
    int tile = bx & 15, ks = bx >> 4;
    int n0 = tile * 64;
    floatx4 accS[2][2], accH[2][2];
#pragma unroll
    for (int i = 0; i < 2; ++i)
#pragma unroll
      for (int j = 0; j < 2; ++j) { accS[i][j] = (floatx4){0.f,0.f,0.f,0.f}; accH[i][j] = (floatx4){0.f,0.f,0.f,0.f}; }
    for (int kc = 0; kc < 8; ++kc) {
      int k0 = ks * 256 + kc * 32;
      __syncthreads();
      stage_bt_bf(x,     FF, 0,  64,   k0, FF, Ah,  Al,  t);
      stage_bt_bf(cent,  FF, n0, 1000, k0, FF, B1h, B1l, t);
      stage_bt_bf(whall, FF, n0, 1000, k0, FF, B2h, B2l, t);
      __syncthreads();
      short8 ah[2], al[2];
#pragma unroll
      for (int i = 0; i < 2; ++i) {
        int row = (mh * 2 + i) * 16 + ln15;
        ah[i] = *(const short8*)(Ah + row * TP + q8);
        al[i] = *(const short8*)(Al + row * TP + q8);
      }
#pragma unroll
      for (int j = 0; j < 2; ++j) {
        int brow = (nh * 2 + j) * 16 + ln15;
        short8 b1h = *(const short8*)(B1h + brow * TP + q8);
        short8 b1l = *(const short8*)(B1l + brow * TP + q8);
        short8 b2h = *(const short8*)(B2h + brow * TP + q8);
        short8 b2l = *(const short8*)(B2l + brow * TP + q8);
#pragma unroll
        for (int i = 0; i < 2; ++i) {
          accS[i][j] = MFMA(ah[i], b1h, accS[i][j]);
          accS[i][j] = MFMA(ah[i], b1l, accS[i][j]);
          accS[i][j] = MFMA(al[i], b1h, accS[i][j]);
          accH[i][j] = MFMA(ah[i], b2h, accH[i][j]);
          accH[i][j] = MFMA(ah[i], b2l, accH[i][j]);
          accH[i][j] = MFMA(al[i], b2h, accH[i][j]);
        }
      }
    }
    float* Spart = ws + OFF_SPART + (size_t)ks * 64000;
    float* Hpart = ws + OFF_HPART + (size_t)ks * 64000;
#pragma unroll
    for (int i = 0; i < 2; ++i)
#pragma unroll
      for (int j = 0; j < 2; ++j) {
        int gn = n0 + (nh * 2 + j) * 16 + ln15;
        if (gn < 1000) {
#pragma unroll
          for (int r = 0; r < 4; ++r) {
            int gm = (mh * 2 + i) * 16 + lq * 4 + r;
            Spart[gm * 1000 + gn] = accS[i][j][r];
            Hpart[gm * 1000 + gn] = accH[i][j][r];
          }
        }
      }
  } else {
    // selpre = x@wsel^T. 32 tiles x 4 splits, slab 512.
    int b2 = bx - 128;
    int tile = b2 & 31, ks = b2 >> 5;
    int n0 = tile * 64;
    floatx4 acc[2][2];
#pragma unroll
    for (int i = 0; i < 2; ++i)
#pragma unroll
      for (int j = 0; j < 2; ++j) acc[i][j] = (floatx4){0.f,0.f,0.f,0.f};
    for (int kc = 0; kc < 16; ++kc) {
      int k0 = ks * 512 + kc * 32;
      __syncthreads();
      stage_bt_bf(x,    FF, 0,  64, k0, FF, Ah,  Al,  t);
      stage_bt_bf(wsel, FF, n0, FF, k0, FF, B1h, B1l, t);
      __syncthreads();
      short8 ah[2], al[2];
#pragma unroll
      for (int i = 0; i < 2; ++i) {
        int row = (mh * 2 + i) * 16 + ln15;
        ah[i] = *(const short8*)(Ah + row * TP + q8);
        al[i] = *(const short8*)(Al + row * TP + q8);
      }
#pragma unroll
      for (int j = 0; j < 2; ++j) {
        int brow = (nh * 2 + j) * 16 + ln15;
        short8 bh = *(const short8*)(B1h + brow * TP + q8);
        short8 bl = *(const short8*)(B1l + brow * TP + q8);
#pragma unroll
        for (int i = 0; i < 2; ++i) {
          acc[i][j] = MFMA(ah[i], bh, acc[i][j]);
          acc[i][j] = MFMA(ah[i], bl, acc[i][j]);
          acc[i][j] = MFMA(al[i], bh, acc[i][j]);
        }
      }
    }
    float* selp = ws + OFF_SELP + (size_t)ks * 131072;
#pragma unroll
    for (int i = 0; i < 2; ++i)
#pragma unroll
      for (int j = 0; j < 2; ++j) {
        int gn = n0 + (nh * 2 + j) * 16 + ln15;
#pragma unroll
        for (int r = 0; r < 4; ++r) {
          int gm = (mh * 2 + i) * 16 + lq * 4 + r;
          selp[gm * 2048 + gn] = acc[i][j][r];
        }
      }
  }

  gbar(bar, NBLK);

  // ---------------- Phase B: min-dist + softmax -> V, reach (blocks 0..63) ----------------
  if (bx < 64) {
    int b = bx;
    const float* Spart = ws + OFF_SPART;
    const float* Hpart = ws + OFF_HPART;
    float xn = ws[OFF_XN2 + b];
    float lmin = 3.0e38f, lmax = -3.0e38f;
    for (int c = t; c < 1000; c += 256) {
      float S = 0.f, H = 0.f;
#pragma unroll
      for (int ks = 0; ks < 8; ++ks) {
        S += Spart[(size_t)ks * 64000 + b * 1000 + c];
        H += Hpart[(size_t)ks * 64000 + b * 1000 + c];
      }
      H += bhall[c];
      hrow[c] = H;
      float d2 = xn - 2.f * S + ws[OFF_CN2 + c];
      lmin = fminf(lmin, d2);
      lmax = fmaxf(lmax, H);
    }
    red[t] = lmin; __syncthreads();
    for (int s = 128; s > 0; s >>= 1) { if (t < s) red[t] = fminf(red[t], red[t + s]); __syncthreads(); }
    float bmin = red[0]; __syncthreads();
    red[t] = lmax; __syncthreads();
    for (int s = 128; s > 0; s >>= 1) { if (t < s) red[t] = fmaxf(red[t], red[t + s]); __syncthreads(); }
    float bmax = red[0]; __syncthreads();
    float lsum = 0.f;
    for (int c = t; c < 1000; c += 256) {
      float e = expf(hrow[c] - bmax);
      hrow[c] = e;
      lsum += e;
    }
    red[t] = lsum; __syncthreads();
    for (int s = 128; s > 0; s >>= 1) { if (t < s) red[t] += red[t + s]; __syncthreads(); }
    float inv = 1.f / red[0];
    float* V = ws + OFF_V;
    for (int c = t; c < 1000; c += 256) V[b * 1000 + c] = hrow[c] * inv;
    if (t == 0) ws[OFF_REACH + b] = 10.f / sqrtf(bmin);
  }

  gbar(bar, 2 * NBLK);

  // ---------------- Phase C: mem = V@cent (K=1000,N=2048). 32 tiles x 8 splits, slab 128 ----------------
  {
    int tile = bx & 31, ks = bx >> 5;
    int n0 = tile * 64;
    const float* V = ws + OFF_V;
    floatx4 acc[2][2];
#pragma unroll
    for (int i = 0; i < 2; ++i)
#pragma unroll
      for (int j = 0; j < 2; ++j) acc[i][j] = (floatx4){0.f,0.f,0.f,0.f};
    for (int kc = 0; kc < 4; ++kc) {
      int k0 = ks * 128 + kc * 32;
      __syncthreads();
      stage_bt_bf(V, 1000, 0, 64, k0, 1000, Ah, Al, t);
      stage_tr_bf(cent, FF, k0, 1000, n0, B1h, B1l, t);
      __syncthreads();
      short8 ah[2], al[2];
#pragma unroll
      for (int i = 0; i < 2; ++i) {
        int row = (mh * 2 + i) * 16 + ln15;
        ah[i] = *(const short8*)(Ah + row * TP + q8);
        al[i] = *(const short8*)(Al + row * TP + q8);
      }
#pragma unroll
      for (int j = 0; j < 2; ++j) {
        int brow = (nh * 2 + j) * 16 + ln15;
        short8 bh = *(const short8*)(B1h + brow * TP + q8);
        short8 bl = *(const short8*)(B1l + brow * TP + q8);
#pragma unroll
        for (int i = 0; i < 2; ++i) {
          acc[i][j] = MFMA(ah[i], bh, acc[i][j]);
          acc[i][j] = MFMA(ah[i], bl, acc[i][j]);
          acc[i][j] = MFMA(al[i], bh, acc[i][j]);
        }
      }
    }
    float* memp = ws + OFF_MEMP + (size_t)ks * 131072;
#pragma unroll
    for (int i = 0; i < 2; ++i)
#pragma unroll
      for (int j = 0; j < 2; ++j) {
        int gn = n0 + (nh * 2 + j) * 16 + ln15;
#pragma unroll
        for (int r = 0; r < 4; ++r) {
          int gm = (mh * 2 + i) * 16 + lq * 4 + r;
          memp[gm * 2048 + gn] = acc[i][j][r];
        }
      }
  }

  gbar(bar, 3 * NBLK);

  // ---------------- Phase D: fuse. 64 rows x 4 chunks of 512 feats ----------------
  {
    int row = bx >> 2, chunk = bx & 3;
    int f0 = chunk * 512;
    const float* selp = ws + OFF_SELP;
    const float* memp = ws + OFF_MEMP;
    float* feat = ws + OFF_FEAT;
    float rch = ws[OFF_REACH + row];
    float nrm2 = 0.f;
#pragma unroll
    for (int ii = 0; ii < 2; ++ii) {
      int f = f0 + ii * 256 + t;
      float sp = bsel[f], mm = 0.f;
#pragma unroll
      for (int ks = 0; ks < 4; ++ks) sp += selp[(size_t)ks * 131072 + row * 2048 + f];
#pragma unroll
      for (int ks = 0; ks < 8; ++ks) mm += memp[(size_t)ks * 131072 + row * 2048 + f];
      float sel = tanhf(sp);
      float inf = sel * mm;
      float xv = x[row * 2048 + f];
      float ft = rch * (xv + inf);
      out[64000 + row * 2048 + f] = xv;     // direct_feature
      out[195072 + row * 2048 + f] = inf;   // infused_feature
      feat[row * 2048 + f] = ft;
      nrm2 += ft * ft;
    }
    __syncthreads();   // LDS re-use guard (red aliases GEMM tiles)
    red[t] = nrm2; __syncthreads();
    for (int s = 128; s > 0; s >>= 1) { if (t < s) red[t] += red[t + s]; __syncthreads(); }
    if (t == 0) ws[OFF_NRM2P + row * 4 + chunk] = red[0];
  }

  gbar(bar, 4 * NBLK);

  // ---------------- Phase E: logp = feat@wcos^T (K=2048,N=1000). 16 tiles x 16 splits, slab 128 ----------------
  {
    int tile = bx & 15, ks = bx >> 4;
    int n0 = tile * 64;
    const float* feat = ws + OFF_FEAT;
    floatx4 acc[2][2];
#pragma unroll
    for (int i = 0; i < 2; ++i)
#pragma unroll
      for (int j = 0; j < 2; ++j) acc[i][j] = (floatx4){0.f,0.f,0.f,0.f};
    for (int kc = 0; kc < 4; ++kc) {
      int k0 = ks * 128 + kc * 32;
      __syncthreads();
      stage_bt_bf(feat, FF, 0,  64,   k0, FF, Ah,  Al,  t);
      stage_bt_bf(wcos, FF, n0, 1000, k0, FF, B1h, B1l, t);
      __syncthreads();
      short8 ah[2], al[2];
#pragma unroll
      for (int i = 0; i < 2; ++i) {
        int row = (mh * 2 + i) * 16 + ln15;
        ah[i] = *(const short8*)(Ah + row * TP + q8);
        al[i] = *(const short8*)(Al + row * TP + q8);
      }
#pragma unroll
      for (int j = 0; j < 2; ++j) {
        int brow = (nh * 2 + j) * 16 + ln15;
        short8 bh = *(const short8*)(B1h + brow * TP + q8);
        short8 bl = *(const short8*)(B1l + brow * TP + q8);
#pragma unroll
        for (int i = 0; i < 2; ++i) {
          acc[i][j] = MFMA(ah[i], bh, acc[i][j]);
          acc[i][j] = MFMA(ah[i], bl, acc[i][j]);
          acc[i][j] = MFMA(al[i], bh, acc[i][j]);
        }
      }
    }
    float* logp = ws + OFF_LOGP + (size_t)ks * 64000;
#pragma unroll
    for (int i = 0; i < 2; ++i)
#pragma unroll
      for (int j = 0; j < 2; ++j) {
        int gn = n0 + (nh * 2 + j) * 16 + ln15;
        if (gn < 1000) {
#pragma unroll
          for (int r = 0; r < 4; ++r) {
            int gm = (mh * 2 + i) * 16 + lq * 4 + r;
            logp[gm * 1000 + gn] = acc[i][j][r];
          }
        }
      }
  }

  gbar(bar, 5 * NBLK);

  // ---------------- Phase F: reduce 16 logit partials, apply cos-norm scales ----------------
  {
    int idx = bx * 250 + t;
    if (t < 250) {
      const float* logp = ws + OFF_LOGP;
      float s = 0.f;
#pragma unroll
      for (int ks = 0; ks < 16; ++ks) s += logp[(size_t)ks * 64000 + idx];
      int b = idx / 1000;
      int c = idx - b * 1000;
      float n2 = ws[OFF_NRM2P + b * 4 + 0] + ws[OFF_NRM2P + b * 4 + 1] +
                 ws[OFF_NRM2P + b * 4 + 2] + ws[OFF_NRM2P + b * 4 + 3];
      float sfac = 16.f / (1.f + sqrtf(n2));
      out[idx] = s * sfac * ws[OFF_WINV + c];
    }
  }
}

extern "C" void kernel_launch(void* const* d_in, const int* in_sizes, int n_in,
                              void* d_out, int out_size, void* d_ws, size_t ws_size,
                              hipStream_t stream) {
  const float* x     = (const float*)d_in[0];
  const float* cent  = (const float*)d_in[1];
  const float* whall = (const float*)d_in[2];
  const float* bhall = (const float*)d_in[3];
  const float* wsel  = (const float*)d_in[4];
  const float* bsel  = (const float*)d_in[5];
  const float* wcos  = (const float*)d_in[6];
  float* out = (float*)d_out;
  float* ws  = (float*)d_ws;
  unsigned* bar = (unsigned*)(ws + OFF_BAR);

  hipLaunchKernelGGL(k_init, dim3(1), dim3(64), 0, stream, bar);
  hipLaunchKernelGGL(k_all, dim3(NBLK), dim3(256), 0, stream,
                     x, cent, whall, bhall, wsel, bsel, wcos, ws, out);
}